// Round 7
// baseline (173.304 us; speedup 1.0000x reference)
//
#include <hip/hip_runtime.h>

// Cuboid (windowed) self-attention, B=2,T=8,H=W=64,C=256, HEADS=8, WS=8.
// Windows: Bw = 2*8*8 = 128, tokens/window N = 8*8*8 = 512, dh = 32.
// Pipeline: k_prep (weightsT->bf16, fold softmax scale*log2e into Q cols)
//           k_qkv  (window-partition + x@qkv_w; Q,K as [bh][n][32], V as V^T [bh][d][n])
//           k_attn (no LDS staging: K/V^T read direct from global (L1/L2-resident);
//                   no-max softmax (shift-invariant, fp32-safe); swapped PV operands
//                   -> O lands store-ready, shuffle-free normalize; only P bounce in LDS)
//           k_proj (O@proj_w + b, window reverse, fp32 out)

typedef __bf16 bf16x8 __attribute__((ext_vector_type(8)));
typedef float f32x4 __attribute__((ext_vector_type(4)));

#define NTOK 512
#define DH 32
#define CDIM 256
#define C3 768

__device__ __forceinline__ unsigned short f2b(float f) {
  unsigned u = __builtin_bit_cast(unsigned, f);
  unsigned r = u + 0x7fffu + ((u >> 16) & 1u);   // RNE, inputs finite
  return (unsigned short)(r >> 16);
}

// ---------------- kernel 0: weight prep ----------------
__global__ void k_prep(const float* __restrict__ qkv_w, const float* __restrict__ proj_w,
                       unsigned short* __restrict__ wqT, unsigned short* __restrict__ wpT) {
  const float QS = 0.2550540254f;  // 32^-0.5 * log2(e)
  int idx = blockIdx.x * 256 + threadIdx.x;
  int stride = gridDim.x * 256;
  for (int i = idx; i < C3 * CDIM; i += stride) {
    int n = i >> 8, kk = i & 255;
    float f = qkv_w[kk * C3 + n];
    if (n < 256) f *= QS;
    wqT[i] = f2b(f);
  }
  for (int i = idx; i < CDIM * CDIM; i += stride) {
    int n = i >> 8, kk = i & 255;
    wpT[i] = f2b(proj_w[kk * CDIM + n]);
  }
}

// ---------------- kernel 1: QKV GEMM (window partition fused) ----------------
// grid 512 blocks, 256 thr. LDS: A full-K [128][264] bf16 + B tile [128][40].
__global__ __launch_bounds__(256, 2) void k_qkv(
    const float* __restrict__ x, const unsigned short* __restrict__ wqT,
    unsigned short* __restrict__ qo, unsigned short* __restrict__ ko,
    unsigned short* __restrict__ vo) {
  extern __shared__ char smem[];
  unsigned short (*As)[264] = (unsigned short (*)[264])smem;
  unsigned short (*Bs)[40]  = (unsigned short (*)[40])(smem + 128 * 264 * 2);
  int tid = threadIdx.x;
  int mtile = blockIdx.x;
  int bw = mtile >> 2;
  int n0 = (mtile & 3) << 7;
  int bb = bw >> 6, hi = (bw >> 3) & 7, wi = bw & 7;

  {  // stage A: rows gathered by window partition, fp32 -> bf16 (native RNE casts)
    int row = tid >> 1;
    int n = n0 + row;
    int tt = n >> 6, ii = (n >> 3) & 7, jj = n & 7;
    const float* src = x + ((((long)(bb * 8 + tt)) * 64 + (hi * 8 + ii)) * 64 + (wi * 8 + jj)) * 256;
    int fb = (tid & 1) * 4;
#pragma unroll
    for (int u = 0; u < 32; ++u) {
      int f = fb + u * 8;
      float4 d = *(const float4*)(src + f);
      __bf16 h0 = (__bf16)d.x, h1 = (__bf16)d.y, h2 = (__bf16)d.z, h3 = (__bf16)d.w;
      __bf16* dst = (__bf16*)&As[row][f];
      dst[0] = h0; dst[1] = h1; dst[2] = h2; dst[3] = h3;
    }
  }
  __syncthreads();

  int wid = tid >> 6, lane = tid & 63;
  int lg = lane >> 4, lr = lane & 15;
  int wr = wid >> 1, wc = wid & 1;

  for (int nt = 0; nt < 6; ++nt) {
    f32x4 acc[4][4];
#pragma unroll
    for (int a = 0; a < 4; ++a)
#pragma unroll
      for (int b2 = 0; b2 < 4; ++b2) acc[a][b2] = (f32x4){0.f, 0.f, 0.f, 0.f};

    for (int kk = 0; kk < 256; kk += 32) {
      __syncthreads();
      {
        int brow = tid >> 1, bh2 = tid & 1;
        const uint4* bs = (const uint4*)(wqT + ((long)(nt * 128 + brow)) * 256 + kk + bh2 * 16);
        uint4 b0 = bs[0], b1 = bs[1];
        *(uint4*)&Bs[brow][bh2 * 16] = b0;
        *(uint4*)&Bs[brow][bh2 * 16 + 8] = b1;
      }
      __syncthreads();
      bf16x8 af[4], bfr[4];
#pragma unroll
      for (int mi = 0; mi < 4; ++mi)
        af[mi] = *(const bf16x8*)&As[wr * 64 + mi * 16 + lr][kk + lg * 8];
#pragma unroll
      for (int ni = 0; ni < 4; ++ni)
        bfr[ni] = *(const bf16x8*)&Bs[wc * 64 + ni * 16 + lr][lg * 8];
#pragma unroll
      for (int mi = 0; mi < 4; ++mi)
#pragma unroll
        for (int ni = 0; ni < 4; ++ni)
          acc[mi][ni] = __builtin_amdgcn_mfma_f32_16x16x32_bf16(af[mi], bfr[ni], acc[mi][ni], 0, 0, 0);
    }
    // epilogue: split q/k/v by output column.
    // Q,K layout [bw*8+head][n][32]; V layout TRANSPOSED [bw*8+head][d][n] (8B packed stores)
#pragma unroll
    for (int ni = 0; ni < 4; ++ni) {
      int c = nt * 128 + wc * 64 + ni * 16 + lr;
      int which = c >> 8, head = (c >> 5) & 7, d = c & 31;
      long base = ((long)(bw * 8 + head)) * NTOK * DH;
      if (which == 2) {
#pragma unroll
        for (int mi = 0; mi < 4; ++mi) {
          int nloc = n0 + wr * 64 + mi * 16 + lg * 4;
          ushort4 w;
          __bf16 v0 = (__bf16)acc[mi][ni][0], v1 = (__bf16)acc[mi][ni][1];
          __bf16 v2 = (__bf16)acc[mi][ni][2], v3 = (__bf16)acc[mi][ni][3];
          w.x = __builtin_bit_cast(unsigned short, v0);
          w.y = __builtin_bit_cast(unsigned short, v1);
          w.z = __builtin_bit_cast(unsigned short, v2);
          w.w = __builtin_bit_cast(unsigned short, v3);
          *(ushort4*)&vo[base + (long)d * NTOK + nloc] = w;
        }
      } else {
        unsigned short* dst = (which == 0) ? qo : ko;
#pragma unroll
        for (int mi = 0; mi < 4; ++mi) {
          int nloc = n0 + wr * 64 + mi * 16 + lg * 4;
#pragma unroll
          for (int r = 0; r < 4; ++r) {
            __bf16 hv = (__bf16)acc[mi][ni][r];
            dst[base + (long)(nloc + r) * DH + d] = __builtin_bit_cast(unsigned short, hv);
          }
        }
      }
    }
  }
}

// ---------------- kernel 2: attention per (window, head) ----------------
// grid 1024 blocks, 256 thr (4 independent waves, no __syncthreads).
// No K/V LDS staging: per-block K (32KB, [n][32] = fragment-ordered, coalesced 1KB
// wave reads) and V^T (32KB, [d][n], 64B-chunk reads) are L1/L2-resident.
// No-max softmax: p = exp2(s) directly (scores |s|<~10, fp32-safe; shift-invariant).
// QK^T swapped: s = mfma(A=K, B=Q^T) -> lane (lg,lr) holds S^T[m=16t+4lg+r][q=lr].
// PV swapped:   o = mfma(A=V^T, B=P) -> lane holds O[q=lr][d=4lg+r(+16)] -> direct
// 8B stores, and the per-q denominators live at q=lr: shuffle-free normalize.
// LDS: only per-wave P bounce [16][80B] (5120B total).
__global__ __launch_bounds__(256, 4) void k_attn(
    const unsigned short* __restrict__ qg0, const unsigned short* __restrict__ kg0,
    const unsigned short* __restrict__ vt0, unsigned short* __restrict__ og) {
  __shared__ char Pall[4 * 1280];
  int bh = blockIdx.x;
  int tid = threadIdx.x;
  const unsigned short* qg = qg0 + (long)bh * NTOK * DH;
  const unsigned short* kg = kg0 + (long)bh * NTOK * DH;
  const unsigned short* vt = vt0 + (long)bh * NTOK * DH;  // [32][512]
  int wid = tid >> 6, lane = tid & 63;
  int lg = lane >> 4, lr = lane & 15;
  char* Pb = Pall + wid * 1280;
  unsigned short* ob = og + (long)bh * NTOK * DH;  // O [n][32]
  const f32x4 zf = {0.f, 0.f, 0.f, 0.f};

  for (int pass = 0; pass < 4; ++pass) {
    int qA = pass * 128 + wid * 32;
    bf16x8 qf0 = *(const bf16x8*)(qg + (qA + lr) * DH + lg * 8);
    bf16x8 qf1 = *(const bf16x8*)(qg + (qA + 16 + lr) * DH + lg * 8);
    f32x4 o00 = zf, o01 = zf, o10 = zf, o11 = zf;
    float ps0 = 0.f, ps1 = 0.f;

    for (int ch = 0; ch < 8; ++ch) {  // 8 chunks of 64 m-columns
      f32x4 s0[4], s1[4];
#pragma unroll
      for (int t = 0; t < 4; ++t) {
        int n = (ch * 4 + t) * 16 + lr;
        bf16x8 kf = *(const bf16x8*)(kg + n * DH + lg * 8);
        s0[t] = __builtin_amdgcn_mfma_f32_16x16x32_bf16(kf, qf0, zf, 0, 0, 0);
        s1[t] = __builtin_amdgcn_mfma_f32_16x16x32_bf16(kf, qf1, zf, 0, 0, 0);
      }
      // p = exp2(s) (Q pre-scaled by scale*log2e); accumulate denominators in-lane
#pragma unroll
      for (int t = 0; t < 4; ++t)
#pragma unroll
        for (int r = 0; r < 4; ++r) {
          float p0 = __builtin_amdgcn_exp2f(s0[t][r]);
          float p1 = __builtin_amdgcn_exp2f(s1[t][r]);
          s0[t][r] = p0; s1[t][r] = p1;
          ps0 += p0; ps1 += p1;
        }
      // PV over 2 groups of 32 m-cols; P bounced via per-wave LDS [16][80B]
#pragma unroll
      for (int mcl = 0; mcl < 2; ++mcl) {
        int mg = ch * 2 + mcl;
        bf16x8 vfA = *(const bf16x8*)(vt + lr * NTOK + mg * 32 + lg * 8);
        bf16x8 vfB = *(const bf16x8*)(vt + (16 + lr) * NTOK + mg * 32 + lg * 8);
        // frag0
#pragma unroll
        for (int u = 0; u < 2; ++u) {
          int t = mcl * 2 + u;
          __bf16* pw = (__bf16*)(Pb + lr * 80 + u * 32 + lg * 8);
          pw[0] = (__bf16)s0[t][0]; pw[1] = (__bf16)s0[t][1];
          pw[2] = (__bf16)s0[t][2]; pw[3] = (__bf16)s0[t][3];
        }
        bf16x8 pf0 = *(const bf16x8*)(Pb + lr * 80 + lg * 16);
        o00 = __builtin_amdgcn_mfma_f32_16x16x32_bf16(vfA, pf0, o00, 0, 0, 0);
        o01 = __builtin_amdgcn_mfma_f32_16x16x32_bf16(vfB, pf0, o01, 0, 0, 0);
        // frag1 (reuse buffer; DS ops in-order within a wave)
#pragma unroll
        for (int u = 0; u < 2; ++u) {
          int t = mcl * 2 + u;
          __bf16* pw = (__bf16*)(Pb + lr * 80 + u * 32 + lg * 8);
          pw[0] = (__bf16)s1[t][0]; pw[1] = (__bf16)s1[t][1];
          pw[2] = (__bf16)s1[t][2]; pw[3] = (__bf16)s1[t][3];
        }
        bf16x8 pf1 = *(const bf16x8*)(Pb + lr * 80 + lg * 16);
        o10 = __builtin_amdgcn_mfma_f32_16x16x32_bf16(vfA, pf1, o10, 0, 0, 0);
        o11 = __builtin_amdgcn_mfma_f32_16x16x32_bf16(vfB, pf1, o11, 0, 0, 0);
      }
    }

    // reduce denominators across lg groups (q = lr identical within each group)
    ps0 += __shfl_xor(ps0, 16, 64);
    ps0 += __shfl_xor(ps0, 32, 64);
    ps1 += __shfl_xor(ps1, 16, 64);
    ps1 += __shfl_xor(ps1, 32, 64);
    float rcp0 = 1.0f / ps0, rcp1 = 1.0f / ps1;

    // store: lane (lg,lr) holds O[q][d=4lg+r] (+16 for oX1) -> packed 8B stores
    {
      ushort4 w;
      __bf16 a0 = (__bf16)(o00[0] * rcp0), a1 = (__bf16)(o00[1] * rcp0);
      __bf16 a2 = (__bf16)(o00[2] * rcp0), a3 = (__bf16)(o00[3] * rcp0);
      w.x = __builtin_bit_cast(unsigned short, a0);
      w.y = __builtin_bit_cast(unsigned short, a1);
      w.z = __builtin_bit_cast(unsigned short, a2);
      w.w = __builtin_bit_cast(unsigned short, a3);
      *(ushort4*)(ob + (long)(qA + lr) * DH + lg * 4) = w;
      __bf16 b0 = (__bf16)(o01[0] * rcp0), b1 = (__bf16)(o01[1] * rcp0);
      __bf16 b2 = (__bf16)(o01[2] * rcp0), b3 = (__bf16)(o01[3] * rcp0);
      w.x = __builtin_bit_cast(unsigned short, b0);
      w.y = __builtin_bit_cast(unsigned short, b1);
      w.z = __builtin_bit_cast(unsigned short, b2);
      w.w = __builtin_bit_cast(unsigned short, b3);
      *(ushort4*)(ob + (long)(qA + lr) * DH + 16 + lg * 4) = w;
      __bf16 c0 = (__bf16)(o10[0] * rcp1), c1 = (__bf16)(o10[1] * rcp1);
      __bf16 c2 = (__bf16)(o10[2] * rcp1), c3 = (__bf16)(o10[3] * rcp1);
      w.x = __builtin_bit_cast(unsigned short, c0);
      w.y = __builtin_bit_cast(unsigned short, c1);
      w.z = __builtin_bit_cast(unsigned short, c2);
      w.w = __builtin_bit_cast(unsigned short, c3);
      *(ushort4*)(ob + (long)(qA + 16 + lr) * DH + lg * 4) = w;
      __bf16 d0 = (__bf16)(o11[0] * rcp1), d1 = (__bf16)(o11[1] * rcp1);
      __bf16 d2 = (__bf16)(o11[2] * rcp1), d3 = (__bf16)(o11[3] * rcp1);
      w.x = __builtin_bit_cast(unsigned short, d0);
      w.y = __builtin_bit_cast(unsigned short, d1);
      w.z = __builtin_bit_cast(unsigned short, d2);
      w.w = __builtin_bit_cast(unsigned short, d3);
      *(ushort4*)(ob + (long)(qA + 16 + lr) * DH + 16 + lg * 4) = w;
    }
  }
}

// ---------------- kernel 3: proj GEMM + bias + window reverse ----------------
__global__ __launch_bounds__(256, 2) void k_proj(
    const unsigned short* __restrict__ og, const unsigned short* __restrict__ wpT,
    const float* __restrict__ pb, float* __restrict__ out) {
  extern __shared__ char smem[];
  unsigned short (*As)[264] = (unsigned short (*)[264])smem;
  unsigned short (*Bs)[40]  = (unsigned short (*)[40])(smem + 128 * 264 * 2);
  int tid = threadIdx.x;
  int mtile = blockIdx.x;
  int bw = mtile >> 2;
  int n0 = (mtile & 3) << 7;
  int bb = bw >> 6, hi = (bw >> 3) & 7, wi = bw & 7;

  {  // stage A from O layout [bw*8+head][n][32]: 64B (4 x uint4) per head per row
    int row = tid >> 1, hf = tid & 1;
#pragma unroll
    for (int h4 = 0; h4 < 4; ++h4) {
      int h = hf * 4 + h4;
      const uint4* asrc = (const uint4*)(og + (((long)(bw * 8 + h)) * NTOK + n0 + row) * DH);
      uint4 d0 = asrc[0], d1 = asrc[1], d2 = asrc[2], d3 = asrc[3];
      *(uint4*)&As[row][h * 32]      = d0;
      *(uint4*)&As[row][h * 32 + 8]  = d1;
      *(uint4*)&As[row][h * 32 + 16] = d2;
      *(uint4*)&As[row][h * 32 + 24] = d3;
    }
  }
  __syncthreads();

  int wid = tid >> 6, lane = tid & 63;
  int lg = lane >> 4, lr = lane & 15;
  int wr = wid >> 1, wc = wid & 1;

  for (int nt = 0; nt < 2; ++nt) {
    f32x4 acc[4][4];
#pragma unroll
    for (int a = 0; a < 4; ++a)
#pragma unroll
      for (int b2 = 0; b2 < 4; ++b2) acc[a][b2] = (f32x4){0.f, 0.f, 0.f, 0.f};

    for (int kk = 0; kk < 256; kk += 32) {
      __syncthreads();
      {
        int brow = tid >> 1, bh2 = tid & 1;
        const uint4* bs = (const uint4*)(wpT + ((long)(nt * 128 + brow)) * 256 + kk + bh2 * 16);
        uint4 b0 = bs[0], b1 = bs[1];
        *(uint4*)&Bs[brow][bh2 * 16] = b0;
        *(uint4*)&Bs[brow][bh2 * 16 + 8] = b1;
      }
      __syncthreads();
      bf16x8 af[4], bfr[4];
#pragma unroll
      for (int mi = 0; mi < 4; ++mi)
        af[mi] = *(const bf16x8*)&As[wr * 64 + mi * 16 + lr][kk + lg * 8];
#pragma unroll
      for (int ni = 0; ni < 4; ++ni)
        bfr[ni] = *(const bf16x8*)&Bs[wc * 64 + ni * 16 + lr][lg * 8];
#pragma unroll
      for (int mi = 0; mi < 4; ++mi)
#pragma unroll
        for (int ni = 0; ni < 4; ++ni)
          acc[mi][ni] = __builtin_amdgcn_mfma_f32_16x16x32_bf16(af[mi], bfr[ni], acc[mi][ni], 0, 0, 0);
    }
    // epilogue: bias + window reverse, coalesced fp32 (16 lanes -> 64B)
#pragma unroll
    for (int ni = 0; ni < 4; ++ni) {
      int c = nt * 128 + wc * 64 + ni * 16 + lr;
      float bias = pb[c];
#pragma unroll
      for (int mi = 0; mi < 4; ++mi) {
        int nbase = n0 + wr * 64 + mi * 16 + lg * 4;
#pragma unroll
        for (int r = 0; r < 4; ++r) {
          int n = nbase + r;
          int tt = n >> 6, ii = (n >> 3) & 7, jj = n & 7;
          long off = ((((long)(bb * 8 + tt)) * 64 + (hi * 8 + ii)) * 64 + (wi * 8 + jj)) * 256 + c;
          out[off] = acc[mi][ni][r] + bias;
        }
      }
    }
  }
}

extern "C" void kernel_launch(void* const* d_in, const int* in_sizes, int n_in,
                              void* d_out, int out_size, void* d_ws, size_t ws_size,
                              hipStream_t stream) {
  const float* x      = (const float*)d_in[0];
  const float* qkv_w  = (const float*)d_in[1];
  const float* proj_w = (const float*)d_in[2];
  const float* proj_b = (const float*)d_in[3];
  float* out = (float*)d_out;
  char* ws = (char*)d_ws;

  // workspace layout (bytes): wqT 393216 | wpT 131072 | Q 32MiB | K 32MiB | V^T 32MiB | O 32MiB
  unsigned short* wqT = (unsigned short*)(ws);
  unsigned short* wpT = (unsigned short*)(ws + 393216);
  unsigned short* Q   = (unsigned short*)(ws + 524288);
  unsigned short* K   = (unsigned short*)(ws + 524288 + 1L * 33554432);
  unsigned short* V   = (unsigned short*)(ws + 524288 + 2L * 33554432);
  unsigned short* O   = (unsigned short*)(ws + 524288 + 3L * 33554432);

  (void)hipFuncSetAttribute((const void*)k_qkv,  hipFuncAttributeMaxDynamicSharedMemorySize, 77824);
  (void)hipFuncSetAttribute((const void*)k_proj, hipFuncAttributeMaxDynamicSharedMemorySize, 77824);

  k_prep<<<256, 256, 0, stream>>>(qkv_w, proj_w, wqT, wpT);
  k_qkv<<<512, 256, 77824, stream>>>(x, wqT, Q, K, V);
  k_attn<<<1024, 256, 0, stream>>>(Q, K, V, O);
  k_proj<<<512, 256, 77824, stream>>>(O, wpT, proj_b, out);
}

// Round 8
// 144.390 us; speedup vs baseline: 1.2002x; 1.2002x over previous
//
#include <hip/hip_runtime.h>

// Cuboid (windowed) self-attention, B=2,T=8,H=W=64,C=256, HEADS=8, WS=8.
// Bw = 128 windows, N = 512 tokens/window, dh = 32, bh = window*8+head (1024).
// k_prep: weightsT->bf16, fold scale*log2e into Q cols.
// k_qkv : window-partition + x@qkv_w; writes Q/K/V in MFMA-fragment chunk order:
//         Qs/Ks[bh][t(16)][ks(2)][h(2)][lane(32)][8elem]  (t = n>>5, ks = d>>4,
//         h = (d>>3)&1, elem j = d&7)   [A-row/B-col = lane&31, k = 8h+j]
//         Vs[bh][mt(16)][kv(2)][h(2)][d(32)][8elem]       (m = mt*32+kv*16+8h+j)
// k_attn: per bh, 4 waves x 128 q. K+V staged once in 64KB linear LDS.
//         32x32x16 MFMAs: S^T = K x Q^T (C: col=q=lane&31, row=m=(r&3)+8(r>>2)+4h).
//         no-max softmax (shift-invariant; |s|<~10 so exp2 is fp32-safe).
//         P -> PV B-operand via v_permlane32_swap_b32 (zero LDS, 4 ops/tile).
//         O = V^T x P accumulated in-register; normalize per-lane; packed stores.
// k_proj: O@proj_w + bias, window reverse, fp32 out.

typedef __bf16 bf16x8 __attribute__((ext_vector_type(8)));
typedef float f32x4 __attribute__((ext_vector_type(4)));
typedef float f32x16 __attribute__((ext_vector_type(16)));

#define NTOK 512
#define DH 32
#define CDIM 256
#define C3 768

__device__ __forceinline__ unsigned short f2b(float f) {
  unsigned u = __builtin_bit_cast(unsigned, f);
  unsigned r = u + 0x7fffu + ((u >> 16) & 1u);   // RNE, inputs finite
  return (unsigned short)(r >> 16);
}

// packed f32->bf16 pair (compiler emits v_cvt_pk_bf16_f32; m240: don't hand-write asm)
__device__ __forceinline__ unsigned pk2(float a, float b) {
  __bf16 x = (__bf16)a, y = (__bf16)b;
  return (unsigned)__builtin_bit_cast(unsigned short, x) |
         ((unsigned)__builtin_bit_cast(unsigned short, y) << 16);
}

// ---------------- kernel 0: weight prep ----------------
__global__ void k_prep(const float* __restrict__ qkv_w, const float* __restrict__ proj_w,
                       unsigned short* __restrict__ wqT, unsigned short* __restrict__ wpT) {
  const float QS = 0.2550540254f;  // 32^-0.5 * log2(e)
  int idx = blockIdx.x * 256 + threadIdx.x;
  int stride = gridDim.x * 256;
  for (int i = idx; i < C3 * CDIM; i += stride) {
    int n = i >> 8, kk = i & 255;
    float f = qkv_w[kk * C3 + n];
    if (n < 256) f *= QS;
    wqT[i] = f2b(f);
  }
  for (int i = idx; i < CDIM * CDIM; i += stride) {
    int n = i >> 8, kk = i & 255;
    wpT[i] = f2b(proj_w[kk * CDIM + n]);
  }
}

// ---------------- kernel 1: QKV GEMM (window partition fused) ----------------
// grid 512 blocks, 256 thr. LDS: A full-K [128][264] bf16 + B tile [128][40].
__global__ __launch_bounds__(256, 2) void k_qkv(
    const float* __restrict__ x, const unsigned short* __restrict__ wqT,
    unsigned short* __restrict__ qo, unsigned short* __restrict__ ko,
    unsigned short* __restrict__ vo) {
  extern __shared__ char smem[];
  unsigned short (*As)[264] = (unsigned short (*)[264])smem;
  unsigned short (*Bs)[40]  = (unsigned short (*)[40])(smem + 128 * 264 * 2);
  int tid = threadIdx.x;
  int mtile = blockIdx.x;
  int bw = mtile >> 2;
  int n0 = (mtile & 3) << 7;
  int bb = bw >> 6, hi = (bw >> 3) & 7, wi = bw & 7;

  {  // stage A: rows gathered by window partition, fp32 -> bf16
    int row = tid >> 1;
    int n = n0 + row;
    int tt = n >> 6, ii = (n >> 3) & 7, jj = n & 7;
    const float* src = x + ((((long)(bb * 8 + tt)) * 64 + (hi * 8 + ii)) * 64 + (wi * 8 + jj)) * 256;
    int fb = (tid & 1) * 4;
#pragma unroll
    for (int u = 0; u < 32; ++u) {
      int f = fb + u * 8;
      float4 d = *(const float4*)(src + f);
      __bf16 h0 = (__bf16)d.x, h1 = (__bf16)d.y, h2 = (__bf16)d.z, h3 = (__bf16)d.w;
      __bf16* dst = (__bf16*)&As[row][f];
      dst[0] = h0; dst[1] = h1; dst[2] = h2; dst[3] = h3;
    }
  }
  __syncthreads();

  int wid = tid >> 6, lane = tid & 63;
  int lg = lane >> 4, lr = lane & 15;
  int wr = wid >> 1, wc = wid & 1;

  for (int nt = 0; nt < 6; ++nt) {
    f32x4 acc[4][4];
#pragma unroll
    for (int a = 0; a < 4; ++a)
#pragma unroll
      for (int b2 = 0; b2 < 4; ++b2) acc[a][b2] = (f32x4){0.f, 0.f, 0.f, 0.f};

    for (int kk = 0; kk < 256; kk += 32) {
      __syncthreads();
      {
        int brow = tid >> 1, bh2 = tid & 1;
        const uint4* bs = (const uint4*)(wqT + ((long)(nt * 128 + brow)) * 256 + kk + bh2 * 16);
        uint4 b0 = bs[0], b1 = bs[1];
        *(uint4*)&Bs[brow][bh2 * 16] = b0;
        *(uint4*)&Bs[brow][bh2 * 16 + 8] = b1;
      }
      __syncthreads();
      bf16x8 af[4], bfr[4];
#pragma unroll
      for (int mi = 0; mi < 4; ++mi)
        af[mi] = *(const bf16x8*)&As[wr * 64 + mi * 16 + lr][kk + lg * 8];
#pragma unroll
      for (int ni = 0; ni < 4; ++ni)
        bfr[ni] = *(const bf16x8*)&Bs[wc * 64 + ni * 16 + lr][lg * 8];
#pragma unroll
      for (int mi = 0; mi < 4; ++mi)
#pragma unroll
        for (int ni = 0; ni < 4; ++ni)
          acc[mi][ni] = __builtin_amdgcn_mfma_f32_16x16x32_bf16(af[mi], bfr[ni], acc[mi][ni], 0, 0, 0);
    }
    // epilogue: split q/k/v; write fragment-chunk layouts (see header comment)
#pragma unroll
    for (int ni = 0; ni < 4; ++ni) {
      int c = nt * 128 + wc * 64 + ni * 16 + lr;
      int which = c >> 8, d = c & 31;
      long base = ((long)(bw * 8 + ((c >> 5) & 7))) * 16384;
      if (which == 2) {
#pragma unroll
        for (int mi = 0; mi < 4; ++mi) {
          int m = n0 + wr * 64 + mi * 16 + lg * 4;
          long off = base + ((long)((m >> 5) * 4 + ((m >> 4) & 1) * 2 + ((m >> 3) & 1)) * 32 + d) * 8 + (m & 7);
          ushort4 w;
          __bf16 v0 = (__bf16)acc[mi][ni][0], v1 = (__bf16)acc[mi][ni][1];
          __bf16 v2 = (__bf16)acc[mi][ni][2], v3 = (__bf16)acc[mi][ni][3];
          w.x = __builtin_bit_cast(unsigned short, v0);
          w.y = __builtin_bit_cast(unsigned short, v1);
          w.z = __builtin_bit_cast(unsigned short, v2);
          w.w = __builtin_bit_cast(unsigned short, v3);
          *(ushort4*)&vo[off] = w;
        }
      } else {
        unsigned short* dst = (which == 0) ? qo : ko;
        int cb = (d >> 4) * 2 + ((d >> 3) & 1);
        int dj = d & 7;
#pragma unroll
        for (int mi = 0; mi < 4; ++mi) {
#pragma unroll
          for (int r = 0; r < 4; ++r) {
            int n = n0 + wr * 64 + mi * 16 + lg * 4 + r;
            long off = base + ((long)((n >> 5) * 4 + cb) * 32 + (n & 31)) * 8 + dj;
            __bf16 hv = (__bf16)acc[mi][ni][r];
            dst[off] = __builtin_bit_cast(unsigned short, hv);
          }
        }
      }
    }
  }
}

// ---------------- kernel 2: attention per (window, head) ----------------
// grid 1024 blocks, 256 thr (4 waves x 128 q). LDS 64KB: K chunks @0, V chunks @32768.
__global__ __launch_bounds__(256, 2) void k_attn(
    const unsigned short* __restrict__ qs0, const unsigned short* __restrict__ ks0,
    const unsigned short* __restrict__ vs0, unsigned short* __restrict__ og) {
  extern __shared__ char smem[];
  int bh = blockIdx.x, tid = threadIdx.x;
  const unsigned short* kg = ks0 + (long)bh * 16384;
  const unsigned short* vg = vs0 + (long)bh * 16384;
#pragma unroll
  for (int i = 0; i < 8; ++i) {
    int ci = tid + i * 256;  // 16B chunks, 2048 per 32KB buffer
    *(uint4*)(smem + ci * 16) = *(const uint4*)(kg + ci * 8);
    *(uint4*)(smem + 32768 + ci * 16) = *(const uint4*)(vg + ci * 8);
  }
  __syncthreads();

  int wid = tid >> 6, lane = tid & 63;
  int l31 = lane & 31, h = lane >> 5;
  const unsigned short* qb = qs0 + (long)bh * 16384;
  unsigned short* ob = og + (long)bh * 16384;
  const f32x16 z16 = {0.f,0.f,0.f,0.f,0.f,0.f,0.f,0.f,0.f,0.f,0.f,0.f,0.f,0.f,0.f,0.f};

  // Q fragments (B-operand): lane supplies Q[q = qt*32 + l31][k = ks*16 + 8h + j]
  bf16x8 qf[4][2];
#pragma unroll
  for (int qt = 0; qt < 4; ++qt)
#pragma unroll
    for (int ks = 0; ks < 2; ++ks)
      qf[qt][ks] = *(const bf16x8*)(qb + ((wid * 4 + qt) * 4 + ks * 2 + h) * 256 + l31 * 8);

  f32x16 o[4];
  float ps[4];
#pragma unroll
  for (int qt = 0; qt < 4; ++qt) { o[qt] = z16; ps[qt] = 0.f; }

  for (int mt = 0; mt < 16; ++mt) {
    // K A-frags (rows m = mt*32 + l31, k = ks*16+8h+j); V A-frags (rows d = l31, k = m-local)
    bf16x8 k0 = *(const bf16x8*)(smem + (mt * 4 + h) * 512 + l31 * 16);
    bf16x8 k1 = *(const bf16x8*)(smem + (mt * 4 + 2 + h) * 512 + l31 * 16);
    bf16x8 v0 = *(const bf16x8*)(smem + 32768 + (mt * 4 + h) * 512 + l31 * 16);
    bf16x8 v1 = *(const bf16x8*)(smem + 32768 + (mt * 4 + 2 + h) * 512 + l31 * 16);
#pragma unroll
    for (int qt = 0; qt < 4; ++qt) {
      // S^T[m][q]: C col=q=l31, row m = (r&3) + 8*(r>>2) + 4h
      f32x16 s = __builtin_amdgcn_mfma_f32_32x32x16_bf16(k0, qf[qt][0], z16, 0, 0, 0);
      s = __builtin_amdgcn_mfma_f32_32x32x16_bf16(k1, qf[qt][1], s, 0, 0, 0);
      float p[16];
#pragma unroll
      for (int r = 0; r < 16; ++r) p[r] = __builtin_amdgcn_exp2f(s[r]);
      ps[qt] += ((((p[0] + p[1]) + (p[2] + p[3])) + ((p[4] + p[5]) + (p[6] + p[7]))) +
                 (((p[8] + p[9]) + (p[10] + p[11])) + ((p[12] + p[13]) + (p[14] + p[15]))));
      // pack to bf16 pairs: w0=m{4h,4h+1} w1=m{4h+2,4h+3} w2=m{8+4h,..} w3=.. (t<16)
      //                     w4..w7 same for m 16..31
      unsigned w0 = pk2(p[0], p[1]),  w1 = pk2(p[2], p[3]);
      unsigned w2 = pk2(p[4], p[5]),  w3 = pk2(p[6], p[7]);
      unsigned w4 = pk2(p[8], p[9]),  w5 = pk2(p[10], p[11]);
      unsigned w6 = pk2(p[12], p[13]), w7 = pk2(p[14], p[15]);
      // dst.hi <-> src.lo: after swap, w0=[w0@h0|w2@h0]=B-word k{0,1}/{8,9}, w2=[w0@h1|w2@h1]=k{4,5}/{12,13}
      asm("v_permlane32_swap_b32 %0, %1" : "+v"(w0), "+v"(w2));
      asm("v_permlane32_swap_b32 %0, %1" : "+v"(w1), "+v"(w3));
      asm("v_permlane32_swap_b32 %0, %1" : "+v"(w4), "+v"(w6));
      asm("v_permlane32_swap_b32 %0, %1" : "+v"(w5), "+v"(w7));
      uint4 pb0u; pb0u.x = w0; pb0u.y = w1; pb0u.z = w2; pb0u.w = w3;
      uint4 pb1u; pb1u.x = w4; pb1u.y = w5; pb1u.z = w6; pb1u.w = w7;
      bf16x8 pb0 = __builtin_bit_cast(bf16x8, pb0u);
      bf16x8 pb1 = __builtin_bit_cast(bf16x8, pb1u);
      // O[d][q] += V^T x P  (C col=q=l31, row d=(r&3)+8(r>>2)+4h)
      o[qt] = __builtin_amdgcn_mfma_f32_32x32x16_bf16(v0, pb0, o[qt], 0, 0, 0);
      o[qt] = __builtin_amdgcn_mfma_f32_32x32x16_bf16(v1, pb1, o[qt], 0, 0, 0);
    }
  }

  // normalize (denominator per q lives in-lane after one h-half reduce) and store
#pragma unroll
  for (int qt = 0; qt < 4; ++qt) {
    float sum = ps[qt] + __shfl_xor(ps[qt], 32, 64);
    float rcp = 1.0f / sum;
    int q = (wid * 4 + qt) * 32 + l31;
#pragma unroll
    for (int s4 = 0; s4 < 4; ++s4) {
      __bf16 b0 = (__bf16)(o[qt][s4 * 4 + 0] * rcp);
      __bf16 b1 = (__bf16)(o[qt][s4 * 4 + 1] * rcp);
      __bf16 b2 = (__bf16)(o[qt][s4 * 4 + 2] * rcp);
      __bf16 b3 = (__bf16)(o[qt][s4 * 4 + 3] * rcp);
      ushort4 w;
      w.x = __builtin_bit_cast(unsigned short, b0);
      w.y = __builtin_bit_cast(unsigned short, b1);
      w.z = __builtin_bit_cast(unsigned short, b2);
      w.w = __builtin_bit_cast(unsigned short, b3);
      // d = 8*s4 + 4h + {0..3}; O layout [bh][n][32]
      *(ushort4*)(ob + q * 32 + s4 * 8 + h * 4) = w;
    }
  }
}

// ---------------- kernel 3: proj GEMM + bias + window reverse ----------------
__global__ __launch_bounds__(256, 2) void k_proj(
    const unsigned short* __restrict__ og, const unsigned short* __restrict__ wpT,
    const float* __restrict__ pb, float* __restrict__ out) {
  extern __shared__ char smem[];
  unsigned short (*As)[264] = (unsigned short (*)[264])smem;
  unsigned short (*Bs)[40]  = (unsigned short (*)[40])(smem + 128 * 264 * 2);
  int tid = threadIdx.x;
  int mtile = blockIdx.x;
  int bw = mtile >> 2;
  int n0 = (mtile & 3) << 7;
  int bb = bw >> 6, hi = (bw >> 3) & 7, wi = bw & 7;

  {  // stage A from O layout [bw*8+head][n][32]
    int row = tid >> 1, hf = tid & 1;
#pragma unroll
    for (int h4 = 0; h4 < 4; ++h4) {
      int h = hf * 4 + h4;
      const uint4* asrc = (const uint4*)(og + (((long)(bw * 8 + h)) * NTOK + n0 + row) * DH);
      uint4 d0 = asrc[0], d1 = asrc[1], d2 = asrc[2], d3 = asrc[3];
      *(uint4*)&As[row][h * 32]      = d0;
      *(uint4*)&As[row][h * 32 + 8]  = d1;
      *(uint4*)&As[row][h * 32 + 16] = d2;
      *(uint4*)&As[row][h * 32 + 24] = d3;
    }
  }
  __syncthreads();

  int wid = tid >> 6, lane = tid & 63;
  int lg = lane >> 4, lr = lane & 15;
  int wr = wid >> 1, wc = wid & 1;

  for (int nt = 0; nt < 2; ++nt) {
    f32x4 acc[4][4];
#pragma unroll
    for (int a = 0; a < 4; ++a)
#pragma unroll
      for (int b2 = 0; b2 < 4; ++b2) acc[a][b2] = (f32x4){0.f, 0.f, 0.f, 0.f};

    for (int kk = 0; kk < 256; kk += 32) {
      __syncthreads();
      {
        int brow = tid >> 1, bh2 = tid & 1;
        const uint4* bs = (const uint4*)(wpT + ((long)(nt * 128 + brow)) * 256 + kk + bh2 * 16);
        uint4 b0 = bs[0], b1 = bs[1];
        *(uint4*)&Bs[brow][bh2 * 16] = b0;
        *(uint4*)&Bs[brow][bh2 * 16 + 8] = b1;
      }
      __syncthreads();
      bf16x8 af[4], bfr[4];
#pragma unroll
      for (int mi = 0; mi < 4; ++mi)
        af[mi] = *(const bf16x8*)&As[wr * 64 + mi * 16 + lr][kk + lg * 8];
#pragma unroll
      for (int ni = 0; ni < 4; ++ni)
        bfr[ni] = *(const bf16x8*)&Bs[wc * 64 + ni * 16 + lr][lg * 8];
#pragma unroll
      for (int mi = 0; mi < 4; ++mi)
#pragma unroll
        for (int ni = 0; ni < 4; ++ni)
          acc[mi][ni] = __builtin_amdgcn_mfma_f32_16x16x32_bf16(af[mi], bfr[ni], acc[mi][ni], 0, 0, 0);
    }
    // epilogue: bias + window reverse, coalesced fp32 (16 lanes -> 64B)
#pragma unroll
    for (int ni = 0; ni < 4; ++ni) {
      int c = nt * 128 + wc * 64 + ni * 16 + lr;
      float bias = pb[c];
#pragma unroll
      for (int mi = 0; mi < 4; ++mi) {
        int nbase = n0 + wr * 64 + mi * 16 + lg * 4;
#pragma unroll
        for (int r = 0; r < 4; ++r) {
          int n = nbase + r;
          int tt = n >> 6, ii = (n >> 3) & 7, jj = n & 7;
          long off = ((((long)(bb * 8 + tt)) * 64 + (hi * 8 + ii)) * 64 + (wi * 8 + jj)) * 256 + c;
          out[off] = acc[mi][ni][r] + bias;
        }
      }
    }
  }
}

extern "C" void kernel_launch(void* const* d_in, const int* in_sizes, int n_in,
                              void* d_out, int out_size, void* d_ws, size_t ws_size,
                              hipStream_t stream) {
  const float* x      = (const float*)d_in[0];
  const float* qkv_w  = (const float*)d_in[1];
  const float* proj_w = (const float*)d_in[2];
  const float* proj_b = (const float*)d_in[3];
  float* out = (float*)d_out;
  char* ws = (char*)d_ws;

  // workspace layout (bytes): wqT 393216 | wpT 131072 | Qs 32MiB | Ks 32MiB | Vs 32MiB | O 32MiB
  unsigned short* wqT = (unsigned short*)(ws);
  unsigned short* wpT = (unsigned short*)(ws + 393216);
  unsigned short* Q   = (unsigned short*)(ws + 524288);
  unsigned short* K   = (unsigned short*)(ws + 524288 + 1L * 33554432);
  unsigned short* V   = (unsigned short*)(ws + 524288 + 2L * 33554432);
  unsigned short* O   = (unsigned short*)(ws + 524288 + 3L * 33554432);

  (void)hipFuncSetAttribute((const void*)k_qkv,  hipFuncAttributeMaxDynamicSharedMemorySize, 77824);
  (void)hipFuncSetAttribute((const void*)k_attn, hipFuncAttributeMaxDynamicSharedMemorySize, 65536);
  (void)hipFuncSetAttribute((const void*)k_proj, hipFuncAttributeMaxDynamicSharedMemorySize, 77824);

  k_prep<<<256, 256, 0, stream>>>(qkv_w, proj_w, wqT, wpT);
  k_qkv<<<512, 256, 77824, stream>>>(x, wqT, Q, K, V);
  k_attn<<<1024, 256, 65536, stream>>>(Q, K, V, O);
  k_proj<<<512, 256, 77824, stream>>>(O, wpT, proj_b, out);
}